// Round 14
// baseline (1311.039 us; speedup 1.0000x reference)
//
#include <hip/hip_runtime.h>
#include <hip/hip_bf16.h>

#define BATCH 4096
#define TSTEPS 80
#define VOCAB 10000
#define EDIM 100
#define UDIM 1024

// LDS (halfs): B weights 4j x 36s x 64lane x 8 = 73728
//            + reduction buffer 4096 (8 KB f32)
//            + 4 K0-wave epilogue scratch 4*640 = 2560  -> 80384 halfs = 160768 B
#define B_HALFS 73728
#define RBUF_HALFS 4096

// s_getreg imm: hwreg(HW_REG_XCC_ID=20, offset=0, size=32) = 20 | (31<<11)
#define HWREG_XCC_ID 63508

typedef _Float16 half8 __attribute__((ext_vector_type(8)));
typedef float float4v __attribute__((ext_vector_type(4)));

// Frag-major layout: chunk(blk, kblk, lane) = 16 B holding
// row = blk*16 + (lane&15), k = kblk*32 + (lane>>4)*8 .. +8.
// h:  [mblk 256][kblk 32][lane]   Wf: [nblk 64][kblk 32][lane]
// xe: [t][mblk 256][kblk 4][lane] Wxf:[nblk 64][kblk 4][lane]

__device__ __forceinline__ void load_lds16(const void* g, void* l) {
    __builtin_amdgcn_global_load_lds(
        (const __attribute__((address_space(1))) unsigned int*)g,
        (__attribute__((address_space(3))) unsigned int*)l,
        16, 0, 0);
}

__device__ __forceinline__ float tanh_fast(float x) {
    return 1.0f - 2.0f / (__expf(2.0f * x) + 1.0f);
}

__global__ __launch_bounds__(256) void convert_wh_frag(const float* __restrict__ Wh,
                                                       _Float16* __restrict__ Wf) {
    int cid = blockIdx.x * 256 + threadIdx.x;
    int lane = cid & 63, kblk = (cid >> 6) & 31, nblk = cid >> 11;
    int n = nblk * 16 + (lane & 15);
    int kb = kblk * 32 + (lane >> 4) * 8;
    half8 v;
    #pragma unroll
    for (int e = 0; e < 8; ++e) v[e] = (_Float16)Wh[(kb + e) * UDIM + n];
    *((half8*)Wf + cid) = v;
}

__global__ __launch_bounds__(256) void convert_wx_frag(const float* __restrict__ Wx,
                                                       _Float16* __restrict__ Wxf) {
    int cid = blockIdx.x * 256 + threadIdx.x;
    int lane = cid & 63, kblk = (cid >> 6) & 3, nblk = cid >> 8;
    int n = nblk * 16 + (lane & 15);
    int kb = kblk * 32 + (lane >> 4) * 8;
    half8 v;
    #pragma unroll
    for (int e = 0; e < 8; ++e)
        v[e] = (kb + e < EDIM) ? (_Float16)Wx[(kb + e) * UDIM + n] : (_Float16)0.0f;
    *((half8*)Wxf + cid) = v;
}

// 2 independent token->emb chains per thread (gather-latency-bound kernel)
__global__ __launch_bounds__(256) void embed_gather_frag(
        const int* __restrict__ inputs, const float* __restrict__ emb,
        _Float16* __restrict__ xe) {
    const int c = blockIdx.x * 256 + threadIdx.x;
    int cid[2] = { c, c + 2621440 };
    const float* src[2];
    int kb[2];
    #pragma unroll
    for (int u = 0; u < 2; ++u) {
        int lane = cid[u] & 63, kblk = (cid[u] >> 6) & 3;
        int mblk = (cid[u] >> 8) & 255, t = cid[u] >> 16;
        int m = mblk * 16 + (lane & 15);
        kb[u] = kblk * 32 + (lane >> 4) * 8;
        int tok = inputs[m * TSTEPS + t];
        src[u] = emb + (size_t)tok * EDIM;
    }
    #pragma unroll
    for (int u = 0; u < 2; ++u) {
        half8 v;
        #pragma unroll
        for (int e = 0; e < 8; ++e)
            v[e] = (kb[u] + e < EDIM) ? (_Float16)src[u][kb[u] + e] : (_Float16)0.0f;
        *((half8*)xe + cid[u]) = v;
    }
}

// Persistent kernel, 256 blocks x 512 threads, 1 block/CU (160.8 KB LDS).
// Tile 256(M) x 64(N), mt = bid&15, nt = bid>>4. K-SPLIT wave layout:
//   wave w: m4 = w&3 (64-row M-tile), kh = w>>2 (K-half).
//   kh=0 (waves 0-3): h slices 14..31; receives reduction, does epilogue.
//   kh=1 (waves 4-7): x slices 0..3 (prefetched as xfma of t+1 during the
//                     previous step's epilogue) + h slices 0..13; writes its
//                     partial acc to LDS for reduction.
// B-LDS reads/CU halve vs r13 (576 frags) with NO A-L2 duplication; MFMA
// unchanged. B slice pinned in LDS all 80 steps; mt-groups closed over their
// h rows; XCD-locality runtime-verified (HW_REG_XCC_ID vote) -> no fences.
__global__ __launch_bounds__(512, 2) void rnn_persist(
        _Float16* __restrict__ hA, _Float16* __restrict__ hB,
        const _Float16* __restrict__ xe,
        const _Float16* __restrict__ Wf, const _Float16* __restrict__ Wxf,
        const float* __restrict__ bias,
        unsigned* vote, unsigned* barg, unsigned* bar)
{
    __shared__ __align__(16) _Float16 smem[B_HALFS + RBUF_HALFS + 4 * 640]; // 160768 B
    __shared__ unsigned sFast;

    const int tid  = threadIdx.x;
    const int lane = tid & 63, wave = tid >> 6;
    const int m4 = wave & 3, kh = wave >> 2;
    const int bid  = blockIdx.x;
    const int mt = bid & 15, nt = bid >> 4;
    const int lrow = lane & 15, lq = lane >> 4;

    // ---- XCD-locality vote + one global barrier (atomics only) ----
    if (tid == 0) {
        unsigned xcd = ((unsigned)__builtin_amdgcn_s_getreg(HWREG_XCC_ID)) & 7u;
        __hip_atomic_fetch_or(&vote[mt], 1u << xcd, __ATOMIC_RELAXED,
                              __HIP_MEMORY_SCOPE_AGENT);
        __builtin_amdgcn_s_waitcnt(0);
        __hip_atomic_fetch_add(barg, 1u, __ATOMIC_RELAXED, __HIP_MEMORY_SCOPE_AGENT);
        while (__hip_atomic_load(barg, __ATOMIC_RELAXED,
                                 __HIP_MEMORY_SCOPE_AGENT) < 256u)
            __builtin_amdgcn_s_sleep(1);
        unsigned allv = 0u, own = 0u;
        for (int g = 0; g < 16; ++g) {
            unsigned v = __hip_atomic_load(&vote[g], __ATOMIC_RELAXED,
                                           __HIP_MEMORY_SCOPE_AGENT);
            allv |= v;
            if (g == mt) own = v;
        }
        const bool single = own != 0u && (own & (own - 1u)) == 0u;
        sFast = (single && __popc(allv) == 8) ? 1u : 0u;
    }
    __syncthreads();
    const bool fast = sFast != 0u;

    // ---- Load B slice into LDS once: [j(4)][s(36)][lane][8]; waves 0-3 ----
    if (wave < 4) {
        const half8* wx8 = (const half8*)Wxf;
        const half8* wh8 = (const half8*)Wf;
        #pragma unroll 1
        for (int s = 0; s < 36; ++s) {
            const half8* src = (s < 4)
                ? wx8 + ((size_t)(nt * 4 + wave) * 4 + s) * 64 + lane
                : wh8 + ((size_t)(nt * 4 + wave) * 32 + (s - 4)) * 64 + lane;
            load_lds16(src, smem + ((wave * 36 + s) * 64 + lane) * 8);
        }
    }
    __syncthreads();

    float4v* rbuf = (float4v*)(smem + B_HALFS);                    // 8 KB
    _Float16* tb  = smem + B_HALFS + RBUF_HALFS + wave * 640;      // K0 only

    float bj[4];
    #pragma unroll
    for (int j = 0; j < 4; ++j) bj[j] = bias[nt * 64 + j * 16 + lrow];

    int mblk[4];                                  // wave tile: 64 M rows
    #pragma unroll
    for (int i = 0; i < 4; ++i) mblk[i] = mt * 16 + m4 * 4 + i;

    unsigned* mybar = bar + mt * 32;   // 128-B padded per-group counter

#define LDB(bf, s) { _Pragma("unroll") \
    for (int j = 0; j < 4; ++j) \
        bf[j] = *(const half8*)&smem[(((j) * 36 + (s)) * 64 + lane) * 8]; }
#define FMAB(A, B) { _Pragma("unroll") \
    for (int i = 0; i < 4; ++i) { _Pragma("unroll") \
        for (int j = 0; j < 4; ++j) \
            acc[i][j] = __builtin_amdgcn_mfma_f32_16x16x32_f16(A[i], B[j], acc[i][j], 0, 0, 0); } }
#define LDH(A, hk) { _Pragma("unroll") \
    for (int i = 0; i < 4; ++i) A[i] = pah[i][(hk) * 64]; }
#define ZACC { _Pragma("unroll") \
    for (int i = 0; i < 4; ++i) { _Pragma("unroll") \
        for (int j = 0; j < 4; ++j) { acc[i][j][0]=0.f; acc[i][j][1]=0.f; acc[i][j][2]=0.f; acc[i][j][3]=0.f; } } }

    float4v acc[4][4];
    half8 a0[4], a1[4], a2[4], b0[4], b1[4];

    // x-segment: acc += xe_tn @ Wx  (B slices 0..3) — K1 waves only
    auto xfma = [&](int tn) {
        const half8* xe8 = (const half8*)xe + (size_t)tn * 65536;
        const half8* px[4];
        #pragma unroll
        for (int i = 0; i < 4; ++i) px[i] = xe8 + (size_t)mblk[i] * 4 * 64 + lane;
        #pragma unroll
        for (int i = 0; i < 4; ++i) { a0[i] = px[i][0]; a1[i] = px[i][64]; a2[i] = px[i][128]; }
        LDB(b0, 0); LDB(b1, 1);
        FMAB(a0, b0); LDB(b0, 2);
        #pragma unroll
        for (int i = 0; i < 4; ++i) a0[i] = px[i][192];
        FMAB(a1, b1); LDB(b1, 3);
        FMAB(a2, b0);
        FMAB(a0, b1);
    };

    ZACC;
    if (kh == 1) xfma(0);

    #pragma unroll 1
    for (int t = 0; t < TSTEPS; ++t) {
        const _Float16* hi = (t & 1) ? hB : hA;
        _Float16*       ho = (t & 1) ? hA : hB;

        const half8* pah[4];
        #pragma unroll
        for (int i = 0; i < 4; ++i)
            pah[i] = (const half8*)hi + (size_t)mblk[i] * 32 * 64 + lane;

        if (kh == 0) {       // h slices s=18..35 (hk 14..31), A dist-3, B dist-2
            LDH(a0, 14); LDH(a1, 15); LDH(a2, 16);
            LDB(b0, 18); LDB(b1, 19);
            FMAB(a0, b0); LDB(b0, 20); LDH(a0, 17);
            FMAB(a1, b1); LDB(b1, 21); LDH(a1, 18);
            FMAB(a2, b0); LDB(b0, 22); LDH(a2, 19);
            FMAB(a0, b1); LDB(b1, 23); LDH(a0, 20);
            FMAB(a1, b0); LDB(b0, 24); LDH(a1, 21);
            FMAB(a2, b1); LDB(b1, 25); LDH(a2, 22);
            FMAB(a0, b0); LDB(b0, 26); LDH(a0, 23);
            FMAB(a1, b1); LDB(b1, 27); LDH(a1, 24);
            FMAB(a2, b0); LDB(b0, 28); LDH(a2, 25);
            FMAB(a0, b1); LDB(b1, 29); LDH(a0, 26);
            FMAB(a1, b0); LDB(b0, 30); LDH(a1, 27);
            FMAB(a2, b1); LDB(b1, 31); LDH(a2, 28);
            FMAB(a0, b0); LDB(b0, 32); LDH(a0, 29);
            FMAB(a1, b1); LDB(b1, 33); LDH(a1, 30);
            FMAB(a2, b0); LDB(b0, 34); LDH(a2, 31);
            FMAB(a0, b1); LDB(b1, 35);
            FMAB(a1, b0);
            FMAB(a2, b1);
        } else {             // acc holds x-part; h slices s=4..17 (hk 0..13)
            LDH(a0, 0); LDH(a1, 1); LDH(a2, 2);
            LDB(b0, 4); LDB(b1, 5);
            FMAB(a0, b0); LDB(b0, 6);  LDH(a0, 3);
            FMAB(a1, b1); LDB(b1, 7);  LDH(a1, 4);
            FMAB(a2, b0); LDB(b0, 8);  LDH(a2, 5);
            FMAB(a0, b1); LDB(b1, 9);  LDH(a0, 6);
            FMAB(a1, b0); LDB(b0, 10); LDH(a1, 7);
            FMAB(a2, b1); LDB(b1, 11); LDH(a2, 8);
            FMAB(a0, b0); LDB(b0, 12); LDH(a0, 9);
            FMAB(a1, b1); LDB(b1, 13); LDH(a1, 10);
            FMAB(a2, b0); LDB(b0, 14); LDH(a2, 11);
            FMAB(a0, b1); LDB(b1, 15); LDH(a0, 12);
            FMAB(a1, b0); LDB(b0, 16); LDH(a1, 13);
            FMAB(a2, b1); LDB(b1, 17);
            FMAB(a0, b0);
            FMAB(a1, b1);
        }

        // ---- K-pair reduction: K1 partial -> K0, f32, 8 KB buffer, 8 rounds ----
        #pragma unroll
        for (int p = 0; p < 4; ++p) {
            #pragma unroll
            for (int ih = 0; ih < 2; ++ih) {
                if (kh == 1 && m4 == p) {
                    #pragma unroll
                    for (int ii = 0; ii < 2; ++ii)
                        #pragma unroll
                        for (int j = 0; j < 4; ++j)
                            rbuf[(ii * 4 + j) * 64 + lane] = acc[ih * 2 + ii][j];
                }
                __syncthreads();
                if (kh == 0 && m4 == p) {
                    #pragma unroll
                    for (int ii = 0; ii < 2; ++ii)
                        #pragma unroll
                        for (int j = 0; j < 4; ++j)
                            acc[ih * 2 + ii][j] += rbuf[(ii * 4 + j) * 64 + lane];
                }
                __syncthreads();
            }
        }

        if (kh == 0) {
            // ---- Epilogue: tanh + C-layout -> A-layout (wave-private LDS) ----
            #pragma unroll
            for (int i = 0; i < 4; ++i) {
                #pragma unroll
                for (int jp = 0; jp < 2; ++jp) {
                    #pragma unroll
                    for (int jj = 0; jj < 2; ++jj) {
                        const int j = jp * 2 + jj;
                        #pragma unroll
                        for (int r = 0; r < 4; ++r)
                            tb[(lq * 4 + r) * 40 + jj * 16 + lrow] =
                                (_Float16)tanh_fast(acc[i][j][r] + bj[j]);
                    }
                    // same-wave LDS RAW -> lgkmcnt only, no barrier
                    half8 v = *(const half8*)&tb[lrow * 40 + lq * 8];
                    *((half8*)ho + (size_t)(mblk[i] * 32 + nt * 2 + jp) * 64 + lane) = v;
                }
            }
            ZACC;
        } else {
            // ---- x-segment of step t+1 overlaps K0's epilogue ----
            ZACC;
            if (t + 1 < TSTEPS) xfma(t + 1);
        }

        // ---- per-group barrier (16 blocks); fences only in fallback mode ----
        if (t < TSTEPS - 1) {
            __syncthreads();    // drains K0 waves' h stores to L2
            if (tid == 0) {
                if (!fast) __builtin_amdgcn_fence(__ATOMIC_RELEASE, "agent");
                __hip_atomic_fetch_add(mybar, 1u, __ATOMIC_RELAXED,
                                       __HIP_MEMORY_SCOPE_AGENT);
                const unsigned target = 16u * (unsigned)(t + 1);
                while (__hip_atomic_load(mybar, __ATOMIC_RELAXED,
                                         __HIP_MEMORY_SCOPE_AGENT) < target)
                    __builtin_amdgcn_s_sleep(1);
                if (!fast) __builtin_amdgcn_fence(__ATOMIC_ACQUIRE, "agent");
            }
            __syncthreads();
        }
    }
#undef LDB
#undef FMAB
#undef LDH
#undef ZACC
}

// out[b] = h[b,:].Wo + bo, h frag-major
__global__ __launch_bounds__(256) void out_proj(const _Float16* __restrict__ h,
                                                const float* __restrict__ Wo,
                                                const float* __restrict__ bo,
                                                float* __restrict__ out) {
    const int lane = threadIdx.x & 63;
    const int wave = threadIdx.x >> 6;
    const int row = blockIdx.x * 4 + wave;
    const int mblk = row >> 4, lb = row & 15;
    const half8* hf = (const half8*)h;
    float s = 0.0f;
    #pragma unroll
    for (int c = 0; c < 2; ++c) {
        const int kblk = lane >> 1;
        const int q = (lane & 1) * 2 + c;
        half8 v = hf[(size_t)(mblk * 32 + kblk) * 64 + lb + q * 16];
        const int k0 = kblk * 32 + q * 8;
        #pragma unroll
        for (int e = 0; e < 8; ++e) s += (float)v[e] * Wo[k0 + e];
    }
    #pragma unroll
    for (int off = 32; off > 0; off >>= 1) s += __shfl_down(s, off, 64);
    if (lane == 0) out[row] = s + bo[0];
}

extern "C" void kernel_launch(void* const* d_in, const int* in_sizes, int n_in,
                              void* d_out, int out_size, void* d_ws, size_t ws_size,
                              hipStream_t stream) {
    const int*   inputs = (const int*)  d_in[0];
    const float* emb    = (const float*)d_in[1];
    const float* Wx     = (const float*)d_in[2];
    const float* Wh     = (const float*)d_in[3];
    const float* b      = (const float*)d_in[4];
    const float* Wo     = (const float*)d_in[5];
    const float* bo     = (const float*)d_in[6];
    float* out = (float*)d_out;

    char* ws = (char*)d_ws;
    _Float16* Wf   = (_Float16*)ws;                          // 2 MB
    _Float16* Wxf  = (_Float16*)(ws + (2u  << 20));          // 256 KB
    _Float16* hA   = (_Float16*)(ws + (3u  << 20));          // 8 MB
    _Float16* hB   = (_Float16*)(ws + (11u << 20));          // 8 MB
    _Float16* xe   = (_Float16*)(ws + (19u << 20));          // 84 MB
    unsigned* vote = (unsigned*)(ws + (103u << 20));         // 16 u32
    unsigned* barg = vote + 16;                              // 1 u32
    unsigned* bar  = vote + 256;                             // 16 x 32-u32 stride

    convert_wh_frag<<<dim3(512),     dim3(256), 0, stream>>>(Wh, Wf);
    convert_wx_frag<<<dim3(64),      dim3(256), 0, stream>>>(Wx, Wxf);
    embed_gather_frag<<<dim3(10240), dim3(256), 0, stream>>>(inputs, emb, xe);
    hipMemsetAsync(hA, 0, (size_t)BATCH * UDIM * sizeof(_Float16), stream);
    hipMemsetAsync(vote, 0, 8192, stream);

    rnn_persist<<<dim3(256), dim3(512), 0, stream>>>(hA, hB, xe, Wf, Wxf, b,
                                                     vote, barg, bar);

    // T=80 even -> final h in hA
    out_proj<<<dim3(1024), dim3(256), 0, stream>>>(hA, Wo, bo, out);
}

// Round 15
// 969.768 us; speedup vs baseline: 1.3519x; 1.3519x over previous
//
#include <hip/hip_runtime.h>
#include <hip/hip_bf16.h>

#define BATCH 4096
#define TSTEPS 80
#define VOCAB 10000
#define EDIM 100
#define UDIM 1024

// LDS: B weights 4 j x 36 s x 64 lanes x 16 B = 147456 B
//      + 8 waves x 640-half epilogue scratch = 10240 B -> 157696 B static
#define B_HALFS 73728

// s_getreg imm: hwreg(HW_REG_XCC_ID=20, offset=0, size=32) = 20 | (31<<11)
#define HWREG_XCC_ID 63508

typedef _Float16 half8 __attribute__((ext_vector_type(8)));
typedef float float4v __attribute__((ext_vector_type(4)));

// Frag-major layout: chunk(blk, kblk, lane) = 16 B holding
// row = blk*16 + (lane&15), k = kblk*32 + (lane>>4)*8 .. +8.
// h:  [mblk 256][kblk 32][lane]   Wf: [nblk 64][kblk 32][lane]
// xe: [t][mblk 256][kblk 4][lane] Wxf:[nblk 64][kblk 4][lane]

__device__ __forceinline__ void load_lds16(const void* g, void* l) {
    __builtin_amdgcn_global_load_lds(
        (const __attribute__((address_space(1))) unsigned int*)g,
        (__attribute__((address_space(3))) unsigned int*)l,
        16, 0, 0);
}

__device__ __forceinline__ float tanh_fast(float x) {
    return 1.0f - 2.0f / (__expf(2.0f * x) + 1.0f);
}

__global__ __launch_bounds__(256) void convert_wh_frag(const float* __restrict__ Wh,
                                                       _Float16* __restrict__ Wf) {
    int cid = blockIdx.x * 256 + threadIdx.x;
    int lane = cid & 63, kblk = (cid >> 6) & 31, nblk = cid >> 11;
    int n = nblk * 16 + (lane & 15);
    int kb = kblk * 32 + (lane >> 4) * 8;
    half8 v;
    #pragma unroll
    for (int e = 0; e < 8; ++e) v[e] = (_Float16)Wh[(kb + e) * UDIM + n];
    *((half8*)Wf + cid) = v;
}

__global__ __launch_bounds__(256) void convert_wx_frag(const float* __restrict__ Wx,
                                                       _Float16* __restrict__ Wxf) {
    int cid = blockIdx.x * 256 + threadIdx.x;
    int lane = cid & 63, kblk = (cid >> 6) & 3, nblk = cid >> 8;
    int n = nblk * 16 + (lane & 15);
    int kb = kblk * 32 + (lane >> 4) * 8;
    half8 v;
    #pragma unroll
    for (int e = 0; e < 8; ++e)
        v[e] = (kb + e < EDIM) ? (_Float16)Wx[(kb + e) * UDIM + n] : (_Float16)0.0f;
    *((half8*)Wxf + cid) = v;
}

// 2 independent token->emb chains per thread (gather-latency-bound kernel)
__global__ __launch_bounds__(256) void embed_gather_frag(
        const int* __restrict__ inputs, const float* __restrict__ emb,
        _Float16* __restrict__ xe) {
    const int c = blockIdx.x * 256 + threadIdx.x;
    int cid[2] = { c, c + 2621440 };
    const float* src[2];
    int kb[2];
    #pragma unroll
    for (int u = 0; u < 2; ++u) {
        int lane = cid[u] & 63, kblk = (cid[u] >> 6) & 3;
        int mblk = (cid[u] >> 8) & 255, t = cid[u] >> 16;
        int m = mblk * 16 + (lane & 15);
        kb[u] = kblk * 32 + (lane >> 4) * 8;
        int tok = inputs[m * TSTEPS + t];
        src[u] = emb + (size_t)tok * EDIM;
    }
    #pragma unroll
    for (int u = 0; u < 2; ++u) {
        half8 v;
        #pragma unroll
        for (int e = 0; e < 8; ++e)
            v[e] = (kb[u] + e < EDIM) ? (_Float16)src[u][kb[u] + e] : (_Float16)0.0f;
        *((half8*)xe + cid[u]) = v;
    }
}

// Persistent kernel, 256 blocks x 512 threads (2 waves/SIMD; 157.7 KB LDS
// keeps 1 block/CU). Tile 256(M) x 64(N), waves split M only (32M x 64N).
// B pinned in LDS all 80 steps; B register-double-buffered (dist 2);
// x-segment of t+1 computed before the barrier. NEW vs r13: waves 4-7 (the
// SIMD partners of waves 0-3) process h-slices ROTATED by 16, so one wave's
// ds_read burst aligns with its partner's MFMA phase — de-correlated
// lgkmcnt stalls instead of lockstep contention. mt-groups closed over h
// rows; XCD-locality runtime-verified (HW_REG_XCC_ID vote) -> no fences.
__global__ __launch_bounds__(512, 2) void rnn_persist(
        _Float16* __restrict__ hA, _Float16* __restrict__ hB,
        const _Float16* __restrict__ xe,
        const _Float16* __restrict__ Wf, const _Float16* __restrict__ Wxf,
        const float* __restrict__ bias,
        unsigned* vote, unsigned* barg, unsigned* bar)
{
    __shared__ __align__(16) _Float16 smem[B_HALFS + 8 * 640];  // 157696 B
    __shared__ unsigned sFast;

    const int tid  = threadIdx.x;
    const int lane = tid & 63, wave = tid >> 6;
    const int bid  = blockIdx.x;
    const int mt = bid & 15, nt = bid >> 4;
    const int lrow = lane & 15, lq = lane >> 4;
    const int rot = (wave >> 2) << 4;              // 0 for waves 0-3, 16 for 4-7

    // ---- XCD-locality vote + one global barrier (atomics only) ----
    if (tid == 0) {
        unsigned xcd = ((unsigned)__builtin_amdgcn_s_getreg(HWREG_XCC_ID)) & 7u;
        __hip_atomic_fetch_or(&vote[mt], 1u << xcd, __ATOMIC_RELAXED,
                              __HIP_MEMORY_SCOPE_AGENT);
        __builtin_amdgcn_s_waitcnt(0);
        __hip_atomic_fetch_add(barg, 1u, __ATOMIC_RELAXED, __HIP_MEMORY_SCOPE_AGENT);
        while (__hip_atomic_load(barg, __ATOMIC_RELAXED,
                                 __HIP_MEMORY_SCOPE_AGENT) < 256u)
            __builtin_amdgcn_s_sleep(1);
        unsigned allv = 0u, own = 0u;
        for (int g = 0; g < 16; ++g) {
            unsigned v = __hip_atomic_load(&vote[g], __ATOMIC_RELAXED,
                                           __HIP_MEMORY_SCOPE_AGENT);
            allv |= v;
            if (g == mt) own = v;
        }
        const bool single = own != 0u && (own & (own - 1u)) == 0u;
        sFast = (single && __popc(allv) == 8) ? 1u : 0u;
    }
    __syncthreads();
    const bool fast = sFast != 0u;

    // ---- Load B slice into LDS once: [j(4)][s(36)][lane][8]; waves 0-3 ----
    if (wave < 4) {
        const half8* wx8 = (const half8*)Wxf;
        const half8* wh8 = (const half8*)Wf;
        #pragma unroll 1
        for (int s = 0; s < 36; ++s) {
            const half8* src = (s < 4)
                ? wx8 + ((size_t)(nt * 4 + wave) * 4 + s) * 64 + lane
                : wh8 + ((size_t)(nt * 4 + wave) * 32 + (s - 4)) * 64 + lane;
            load_lds16(src, smem + ((wave * 36 + s) * 64 + lane) * 8);
        }
    }
    __syncthreads();

    _Float16* tb = smem + B_HALFS + wave * 640;   // epilogue scratch, wave-private

    float bj[4];
    #pragma unroll
    for (int j = 0; j < 4; ++j) bj[j] = bias[nt * 64 + j * 16 + lrow];

    int mblk[2];                                  // wave tile: 32 M rows
    #pragma unroll
    for (int i = 0; i < 2; ++i) mblk[i] = mt * 16 + wave * 2 + i;

    unsigned* mybar = bar + mt * 32;   // 128-B padded per-group counter

#define LDB(bf, s) { _Pragma("unroll") \
    for (int j = 0; j < 4; ++j) \
        bf[j] = *(const half8*)&smem[(((j) * 36 + (s)) * 64 + lane) * 8]; }
#define FMAB(A, B) { _Pragma("unroll") \
    for (int i = 0; i < 2; ++i) { _Pragma("unroll") \
        for (int j = 0; j < 4; ++j) \
            acc[i][j] = __builtin_amdgcn_mfma_f32_16x16x32_f16(A[i], B[j], acc[i][j], 0, 0, 0); } }
#define LDH(A, hk) { _Pragma("unroll") \
    for (int i = 0; i < 2; ++i) A[i] = pah[i][(hk) * 64]; }
#define ZACC { _Pragma("unroll") \
    for (int i = 0; i < 2; ++i) { _Pragma("unroll") \
        for (int j = 0; j < 4; ++j) { acc[i][j][0]=0.f; acc[i][j][1]=0.f; acc[i][j][2]=0.f; acc[i][j][3]=0.f; } } }
#define HK(p) (((p) + rot) & 31)

    float4v acc[2][4];
    half8 a0[2], a1[2], a2[2], a3[2], b0[4], b1[4];

    // x-segment for a step: acc += xe_tn @ Wx  (B slices 0..3, no rotation)
    auto xfma = [&](int tn) {
        const half8* xe8 = (const half8*)xe + (size_t)tn * 65536;
        #pragma unroll
        for (int i = 0; i < 2; ++i) {
            const half8* px = xe8 + (size_t)mblk[i] * 4 * 64 + lane;
            a0[i] = px[0]; a1[i] = px[64]; a2[i] = px[128]; a3[i] = px[192];
        }
        LDB(b0, 0); LDB(b1, 1);
        FMAB(a0, b0); LDB(b0, 2);
        FMAB(a1, b1); LDB(b1, 3);
        FMAB(a2, b0);
        FMAB(a3, b1);
    };

    ZACC;
    xfma(0);

    #pragma unroll 1
    for (int t = 0; t < TSTEPS; ++t) {
        const _Float16* hi = (t & 1) ? hB : hA;
        _Float16*       ho = (t & 1) ? hA : hB;

        const half8* pah[2];
        #pragma unroll
        for (int i = 0; i < 2; ++i)
            pah[i] = (const half8*)hi + (size_t)mblk[i] * 32 * 64 + lane;

        // ---- h-loop: 32 slices in wave-rotated order (HK), A dist-4 + B dist-2 ----
        LDH(a0, HK(0)); LDH(a1, HK(1)); LDH(a2, HK(2)); LDH(a3, HK(3));
        LDB(b0, 4 + HK(0)); LDB(b1, 4 + HK(1));
        #pragma unroll 1
        for (int p = 0; p < 28; p += 4) {
            FMAB(a0, b0); LDB(b0, 4 + HK(p + 2)); LDH(a0, HK(p + 4));
            FMAB(a1, b1); LDB(b1, 4 + HK(p + 3)); LDH(a1, HK(p + 5));
            FMAB(a2, b0); LDB(b0, 4 + HK(p + 4)); LDH(a2, HK(p + 6));
            FMAB(a3, b1); LDB(b1, 4 + HK(p + 5)); LDH(a3, HK(p + 7));
        }
        // tail: logical p = 28..31
        FMAB(a0, b0); LDB(b0, 4 + HK(30));
        FMAB(a1, b1); LDB(b1, 4 + HK(31));
        FMAB(a2, b0);
        FMAB(a3, b1);

        // ---- Epilogue: tanh + C-layout -> A-layout (wave-private LDS) ----
        #pragma unroll
        for (int i = 0; i < 2; ++i) {
            #pragma unroll
            for (int jp = 0; jp < 2; ++jp) {
                #pragma unroll
                for (int jj = 0; jj < 2; ++jj) {
                    const int j = jp * 2 + jj;
                    #pragma unroll
                    for (int r = 0; r < 4; ++r)
                        tb[(lq * 4 + r) * 40 + jj * 16 + lrow] =
                            (_Float16)tanh_fast(acc[i][j][r] + bj[j]);
                }
                // same-wave LDS RAW -> lgkmcnt only, no barrier
                half8 v = *(const half8*)&tb[lrow * 40 + lq * 8];
                *((half8*)ho + (size_t)(mblk[i] * 32 + nt * 2 + jp) * 64 + lane) = v;
            }
        }

        // ---- x-segment of step t+1 (independent of h_{t+1}) BEFORE barrier ----
        if (t < TSTEPS - 1) {
            ZACC;
            xfma(t + 1);
            __syncthreads();    // drains all waves' h stores to L2
            if (tid == 0) {
                if (!fast) __builtin_amdgcn_fence(__ATOMIC_RELEASE, "agent");
                __hip_atomic_fetch_add(mybar, 1u, __ATOMIC_RELAXED,
                                       __HIP_MEMORY_SCOPE_AGENT);
                const unsigned target = 16u * (unsigned)(t + 1);
                while (__hip_atomic_load(mybar, __ATOMIC_RELAXED,
                                         __HIP_MEMORY_SCOPE_AGENT) < target)
                    __builtin_amdgcn_s_sleep(1);
                if (!fast) __builtin_amdgcn_fence(__ATOMIC_ACQUIRE, "agent");
            }
            __syncthreads();
        }
    }
#undef LDB
#undef FMAB
#undef LDH
#undef ZACC
#undef HK
}

// out[b] = h[b,:].Wo + bo, h frag-major
__global__ __launch_bounds__(256) void out_proj(const _Float16* __restrict__ h,
                                                const float* __restrict__ Wo,
                                                const float* __restrict__ bo,
                                                float* __restrict__ out) {
    const int lane = threadIdx.x & 63;
    const int wave = threadIdx.x >> 6;
    const int row = blockIdx.x * 4 + wave;
    const int mblk = row >> 4, lb = row & 15;
    const half8* hf = (const half8*)h;
    float s = 0.0f;
    #pragma unroll
    for (int c = 0; c < 2; ++c) {
        const int kblk = lane >> 1;
        const int q = (lane & 1) * 2 + c;
        half8 v = hf[(size_t)(mblk * 32 + kblk) * 64 + lb + q * 16];
        const int k0 = kblk * 32 + q * 8;
        #pragma unroll
        for (int e = 0; e < 8; ++e) s += (float)v[e] * Wo[k0 + e];
    }
    #pragma unroll
    for (int off = 32; off > 0; off >>= 1) s += __shfl_down(s, off, 64);
    if (lane == 0) out[row] = s + bo[0];
}

extern "C" void kernel_launch(void* const* d_in, const int* in_sizes, int n_in,
                              void* d_out, int out_size, void* d_ws, size_t ws_size,
                              hipStream_t stream) {
    const int*   inputs = (const int*)  d_in[0];
    const float* emb    = (const float*)d_in[1];
    const float* Wx     = (const float*)d_in[2];
    const float* Wh     = (const float*)d_in[3];
    const float* b      = (const float*)d_in[4];
    const float* Wo     = (const float*)d_in[5];
    const float* bo     = (const float*)d_in[6];
    float* out = (float*)d_out;

    char* ws = (char*)d_ws;
    _Float16* Wf   = (_Float16*)ws;                          // 2 MB
    _Float16* Wxf  = (_Float16*)(ws + (2u  << 20));          // 256 KB
    _Float16* hA   = (_Float16*)(ws + (3u  << 20));          // 8 MB
    _Float16* hB   = (_Float16*)(ws + (11u << 20));          // 8 MB
    _Float16* xe   = (_Float16*)(ws + (19u << 20));          // 84 MB
    unsigned* vote = (unsigned*)(ws + (103u << 20));         // 16 u32
    unsigned* barg = vote + 16;                              // 1 u32
    unsigned* bar  = vote + 256;                             // 16 x 32-u32 stride

    convert_wh_frag<<<dim3(512),     dim3(256), 0, stream>>>(Wh, Wf);
    convert_wx_frag<<<dim3(64),      dim3(256), 0, stream>>>(Wx, Wxf);
    embed_gather_frag<<<dim3(10240), dim3(256), 0, stream>>>(inputs, emb, xe);
    hipMemsetAsync(hA, 0, (size_t)BATCH * UDIM * sizeof(_Float16), stream);
    hipMemsetAsync(vote, 0, 8192, stream);

    rnn_persist<<<dim3(256), dim3(512), 0, stream>>>(hA, hB, xe, Wf, Wxf, b,
                                                     vote, barg, bar);

    // T=80 even -> final h in hA
    out_proj<<<dim3(1024), dim3(256), 0, stream>>>(hA, Wo, bo, out);
}

// Round 16
// 947.033 us; speedup vs baseline: 1.3844x; 1.0240x over previous
//
#include <hip/hip_runtime.h>
#include <hip/hip_bf16.h>

#define BATCH 4096
#define TSTEPS 80
#define VOCAB 10000
#define EDIM 100
#define UDIM 1024

// LDS: B weights 4 j x 36 s x 64 lanes x 16 B = 147456 B
//      + 8 waves x 640-half epilogue scratch = 10240 B -> 157696 B static
#define B_HALFS 73728

// s_getreg imm: hwreg(HW_REG_XCC_ID=20, offset=0, size=32) = 20 | (31<<11)
#define HWREG_XCC_ID 63508

typedef _Float16 half8 __attribute__((ext_vector_type(8)));
typedef float float4v __attribute__((ext_vector_type(4)));

// Frag-major layout: chunk(blk, kblk, lane) = 16 B holding
// row = blk*16 + (lane&15), k = kblk*32 + (lane>>4)*8 .. +8.
// h:  [mblk 256][kblk 32][lane]   Wf: [nblk 64][kblk 32][lane]
// xe: [t][mblk 256][kblk 4][lane] Wxf:[nblk 64][kblk 4][lane]

__device__ __forceinline__ void load_lds16(const void* g, void* l) {
    __builtin_amdgcn_global_load_lds(
        (const __attribute__((address_space(1))) unsigned int*)g,
        (__attribute__((address_space(3))) unsigned int*)l,
        16, 0, 0);
}

__device__ __forceinline__ float tanh_fast(float x) {
    return 1.0f - 2.0f / (__expf(2.0f * x) + 1.0f);
}

__global__ __launch_bounds__(256) void convert_wh_frag(const float* __restrict__ Wh,
                                                       _Float16* __restrict__ Wf) {
    int cid = blockIdx.x * 256 + threadIdx.x;
    int lane = cid & 63, kblk = (cid >> 6) & 31, nblk = cid >> 11;
    int n = nblk * 16 + (lane & 15);
    int kb = kblk * 32 + (lane >> 4) * 8;
    half8 v;
    #pragma unroll
    for (int e = 0; e < 8; ++e) v[e] = (_Float16)Wh[(kb + e) * UDIM + n];
    *((half8*)Wf + cid) = v;
}

__global__ __launch_bounds__(256) void convert_wx_frag(const float* __restrict__ Wx,
                                                       _Float16* __restrict__ Wxf) {
    int cid = blockIdx.x * 256 + threadIdx.x;
    int lane = cid & 63, kblk = (cid >> 6) & 3, nblk = cid >> 8;
    int n = nblk * 16 + (lane & 15);
    int kb = kblk * 32 + (lane >> 4) * 8;
    half8 v;
    #pragma unroll
    for (int e = 0; e < 8; ++e)
        v[e] = (kb + e < EDIM) ? (_Float16)Wx[(kb + e) * UDIM + n] : (_Float16)0.0f;
    *((half8*)Wxf + cid) = v;
}

// 2 independent token->emb chains per thread (gather-latency-bound kernel)
__global__ __launch_bounds__(256) void embed_gather_frag(
        const int* __restrict__ inputs, const float* __restrict__ emb,
        _Float16* __restrict__ xe) {
    const int c = blockIdx.x * 256 + threadIdx.x;
    int cid[2] = { c, c + 2621440 };
    const float* src[2];
    int kb[2];
    #pragma unroll
    for (int u = 0; u < 2; ++u) {
        int lane = cid[u] & 63, kblk = (cid[u] >> 6) & 3;
        int mblk = (cid[u] >> 8) & 255, t = cid[u] >> 16;
        int m = mblk * 16 + (lane & 15);
        kb[u] = kblk * 32 + (lane >> 4) * 8;
        int tok = inputs[m * TSTEPS + t];
        src[u] = emb + (size_t)tok * EDIM;
    }
    #pragma unroll
    for (int u = 0; u < 2; ++u) {
        half8 v;
        #pragma unroll
        for (int e = 0; e < 8; ++e)
            v[e] = (kb[u] + e < EDIM) ? (_Float16)src[u][kb[u] + e] : (_Float16)0.0f;
        *((half8*)xe + cid[u]) = v;
    }
}

// Persistent kernel, 256 blocks x 512 threads (2 waves/SIMD; 157.7 KB LDS
// keeps 1 block/CU). Tile 256(M) x 64(N), waves split M only (32M x 64N).
// B pinned in LDS all 80 steps; B register-double-buffered (dist 2);
// x-segment of t+1 computed before the barrier (r13 schedule — best known).
// NEW: fast-mode group barrier uses DISTRIBUTED per-producer counters
// (parallel RMWs on 16 separate 16-B slots + 16-lane parallel spin) instead
// of 16 serialized fetch_adds on one cacheline. Producer increments its own
// counter only after __syncthreads drained its step-t reads AND writes, so
// waiting for all 16 covers both RAW and WAR — semantics identical to the
// single-counter barrier. mt-groups closed over h rows; XCD-locality
// runtime-verified (HW_REG_XCC_ID vote) -> no cache fences in fast mode.
__global__ __launch_bounds__(512, 2) void rnn_persist(
        _Float16* __restrict__ hA, _Float16* __restrict__ hB,
        const _Float16* __restrict__ xe,
        const _Float16* __restrict__ Wf, const _Float16* __restrict__ Wxf,
        const float* __restrict__ bias,
        unsigned* vote, unsigned* barg, unsigned* bar, unsigned* fbar)
{
    __shared__ __align__(16) _Float16 smem[B_HALFS + 8 * 640];  // 157696 B
    __shared__ unsigned sFast;

    const int tid  = threadIdx.x;
    const int lane = tid & 63, wave = tid >> 6;
    const int bid  = blockIdx.x;
    const int mt = bid & 15, nt = bid >> 4;
    const int lrow = lane & 15, lq = lane >> 4;

    // ---- XCD-locality vote + one global barrier (atomics only) ----
    if (tid == 0) {
        unsigned xcd = ((unsigned)__builtin_amdgcn_s_getreg(HWREG_XCC_ID)) & 7u;
        __hip_atomic_fetch_or(&vote[mt], 1u << xcd, __ATOMIC_RELAXED,
                              __HIP_MEMORY_SCOPE_AGENT);
        __builtin_amdgcn_s_waitcnt(0);
        __hip_atomic_fetch_add(barg, 1u, __ATOMIC_RELAXED, __HIP_MEMORY_SCOPE_AGENT);
        while (__hip_atomic_load(barg, __ATOMIC_RELAXED,
                                 __HIP_MEMORY_SCOPE_AGENT) < 256u)
            __builtin_amdgcn_s_sleep(1);
        unsigned allv = 0u, own = 0u;
        for (int g = 0; g < 16; ++g) {
            unsigned v = __hip_atomic_load(&vote[g], __ATOMIC_RELAXED,
                                           __HIP_MEMORY_SCOPE_AGENT);
            allv |= v;
            if (g == mt) own = v;
        }
        const bool single = own != 0u && (own & (own - 1u)) == 0u;
        sFast = (single && __popc(allv) == 8) ? 1u : 0u;
    }
    __syncthreads();
    const bool fast = sFast != 0u;

    // ---- Load B slice into LDS once: [j(4)][s(36)][lane][8]; waves 0-3 ----
    if (wave < 4) {
        const half8* wx8 = (const half8*)Wxf;
        const half8* wh8 = (const half8*)Wf;
        #pragma unroll 1
        for (int s = 0; s < 36; ++s) {
            const half8* src = (s < 4)
                ? wx8 + ((size_t)(nt * 4 + wave) * 4 + s) * 64 + lane
                : wh8 + ((size_t)(nt * 4 + wave) * 32 + (s - 4)) * 64 + lane;
            load_lds16(src, smem + ((wave * 36 + s) * 64 + lane) * 8);
        }
    }
    __syncthreads();

    _Float16* tb = smem + B_HALFS + wave * 640;   // epilogue scratch, wave-private

    float bj[4];
    #pragma unroll
    for (int j = 0; j < 4; ++j) bj[j] = bias[nt * 64 + j * 16 + lrow];

    int mblk[2];                                  // wave tile: 32 M rows
    #pragma unroll
    for (int i = 0; i < 2; ++i) mblk[i] = mt * 16 + wave * 2 + i;

    unsigned* mybar = bar + mt * 32;              // fallback single counter
    unsigned* mycnt = fbar + (mt * 16 + nt) * 4;  // own producer counter (16 B stride)

#define LDB(bf, s) { _Pragma("unroll") \
    for (int j = 0; j < 4; ++j) \
        bf[j] = *(const half8*)&smem[(((j) * 36 + (s)) * 64 + lane) * 8]; }
#define FMAB(A, B) { _Pragma("unroll") \
    for (int i = 0; i < 2; ++i) { _Pragma("unroll") \
        for (int j = 0; j < 4; ++j) \
            acc[i][j] = __builtin_amdgcn_mfma_f32_16x16x32_f16(A[i], B[j], acc[i][j], 0, 0, 0); } }
#define LDH(A, hk) { _Pragma("unroll") \
    for (int i = 0; i < 2; ++i) A[i] = pah[i][(hk) * 64]; }
#define ZACC { _Pragma("unroll") \
    for (int i = 0; i < 2; ++i) { _Pragma("unroll") \
        for (int j = 0; j < 4; ++j) { acc[i][j][0]=0.f; acc[i][j][1]=0.f; acc[i][j][2]=0.f; acc[i][j][3]=0.f; } } }

    float4v acc[2][4];
    half8 a0[2], a1[2], a2[2], a3[2], b0[4], b1[4];

    // x-segment for a step: acc += xe_tn @ Wx  (B slices 0..3)
    auto xfma = [&](int tn) {
        const half8* xe8 = (const half8*)xe + (size_t)tn * 65536;
        #pragma unroll
        for (int i = 0; i < 2; ++i) {
            const half8* px = xe8 + (size_t)mblk[i] * 4 * 64 + lane;
            a0[i] = px[0]; a1[i] = px[64]; a2[i] = px[128]; a3[i] = px[192];
        }
        LDB(b0, 0); LDB(b1, 1);
        FMAB(a0, b0); LDB(b0, 2);
        FMAB(a1, b1); LDB(b1, 3);
        FMAB(a2, b0);
        FMAB(a3, b1);
    };

    ZACC;
    xfma(0);

    #pragma unroll 1
    for (int t = 0; t < TSTEPS; ++t) {
        const _Float16* hi = (t & 1) ? hB : hA;
        _Float16*       ho = (t & 1) ? hA : hB;

        const half8* pah[2];
        #pragma unroll
        for (int i = 0; i < 2; ++i)
            pah[i] = (const half8*)hi + (size_t)mblk[i] * 32 * 64 + lane;

        // ---- h-loop: 32 slices (B s = hk+4), A dist-4 + B dist-2 pipeline ----
        LDH(a0, 0); LDH(a1, 1); LDH(a2, 2); LDH(a3, 3);
        LDB(b0, 4); LDB(b1, 5);
        #pragma unroll 1
        for (int hk = 0; hk < 28; hk += 4) {
            FMAB(a0, b0); LDB(b0, hk + 6); LDH(a0, hk + 4);
            FMAB(a1, b1); LDB(b1, hk + 7); LDH(a1, hk + 5);
            FMAB(a2, b0); LDB(b0, hk + 8); LDH(a2, hk + 6);
            FMAB(a3, b1); LDB(b1, hk + 9); LDH(a3, hk + 7);
        }
        // tail: slices s = 32..35
        FMAB(a0, b0); LDB(b0, 34);
        FMAB(a1, b1); LDB(b1, 35);
        FMAB(a2, b0);
        FMAB(a3, b1);

        // ---- Epilogue: tanh + C-layout -> A-layout (wave-private LDS) ----
        #pragma unroll
        for (int i = 0; i < 2; ++i) {
            #pragma unroll
            for (int jp = 0; jp < 2; ++jp) {
                #pragma unroll
                for (int jj = 0; jj < 2; ++jj) {
                    const int j = jp * 2 + jj;
                    #pragma unroll
                    for (int r = 0; r < 4; ++r)
                        tb[(lq * 4 + r) * 40 + jj * 16 + lrow] =
                            (_Float16)tanh_fast(acc[i][j][r] + bj[j]);
                }
                // same-wave LDS RAW -> lgkmcnt only, no barrier
                half8 v = *(const half8*)&tb[lrow * 40 + lq * 8];
                *((half8*)ho + (size_t)(mblk[i] * 32 + nt * 2 + jp) * 64 + lane) = v;
            }
        }

        // ---- x-segment of step t+1 (independent of h_{t+1}) BEFORE barrier ----
        if (t < TSTEPS - 1) {
            ZACC;
            xfma(t + 1);
            __syncthreads();    // drains all waves' h stores to L2
            if (fast) {
                // distributed barrier: parallel RMWs + 16-lane parallel spin
                if (tid == 0)
                    __hip_atomic_fetch_add(mycnt, 1u, __ATOMIC_RELAXED,
                                           __HIP_MEMORY_SCOPE_AGENT);
                if (tid < 16) {
                    while (__hip_atomic_load(&fbar[(mt * 16 + tid) * 4],
                                             __ATOMIC_RELAXED,
                                             __HIP_MEMORY_SCOPE_AGENT)
                           < (unsigned)(t + 1))
                        __builtin_amdgcn_s_sleep(1);
                }
            } else if (tid == 0) {
                __builtin_amdgcn_fence(__ATOMIC_RELEASE, "agent");
                __hip_atomic_fetch_add(mybar, 1u, __ATOMIC_RELAXED,
                                       __HIP_MEMORY_SCOPE_AGENT);
                const unsigned target = 16u * (unsigned)(t + 1);
                while (__hip_atomic_load(mybar, __ATOMIC_RELAXED,
                                         __HIP_MEMORY_SCOPE_AGENT) < target)
                    __builtin_amdgcn_s_sleep(1);
                __builtin_amdgcn_fence(__ATOMIC_ACQUIRE, "agent");
            }
            __syncthreads();
        }
    }
#undef LDB
#undef FMAB
#undef LDH
#undef ZACC
}

// out[b] = h[b,:].Wo + bo, h frag-major
__global__ __launch_bounds__(256) void out_proj(const _Float16* __restrict__ h,
                                                const float* __restrict__ Wo,
                                                const float* __restrict__ bo,
                                                float* __restrict__ out) {
    const int lane = threadIdx.x & 63;
    const int wave = threadIdx.x >> 6;
    const int row = blockIdx.x * 4 + wave;
    const int mblk = row >> 4, lb = row & 15;
    const half8* hf = (const half8*)h;
    float s = 0.0f;
    #pragma unroll
    for (int c = 0; c < 2; ++c) {
        const int kblk = lane >> 1;
        const int q = (lane & 1) * 2 + c;
        half8 v = hf[(size_t)(mblk * 32 + kblk) * 64 + lb + q * 16];
        const int k0 = kblk * 32 + q * 8;
        #pragma unroll
        for (int e = 0; e < 8; ++e) s += (float)v[e] * Wo[k0 + e];
    }
    #pragma unroll
    for (int off = 32; off > 0; off >>= 1) s += __shfl_down(s, off, 64);
    if (lane == 0) out[row] = s + bo[0];
}

extern "C" void kernel_launch(void* const* d_in, const int* in_sizes, int n_in,
                              void* d_out, int out_size, void* d_ws, size_t ws_size,
                              hipStream_t stream) {
    const int*   inputs = (const int*)  d_in[0];
    const float* emb    = (const float*)d_in[1];
    const float* Wx     = (const float*)d_in[2];
    const float* Wh     = (const float*)d_in[3];
    const float* b      = (const float*)d_in[4];
    const float* Wo     = (const float*)d_in[5];
    const float* bo     = (const float*)d_in[6];
    float* out = (float*)d_out;

    char* ws = (char*)d_ws;
    _Float16* Wf   = (_Float16*)ws;                          // 2 MB
    _Float16* Wxf  = (_Float16*)(ws + (2u  << 20));          // 256 KB
    _Float16* hA   = (_Float16*)(ws + (3u  << 20));          // 8 MB
    _Float16* hB   = (_Float16*)(ws + (11u << 20));          // 8 MB
    _Float16* xe   = (_Float16*)(ws + (19u << 20));          // 84 MB
    unsigned* vote = (unsigned*)(ws + (103u << 20));         // 16 u32
    unsigned* barg = vote + 16;                              // 1 u32
    unsigned* bar  = vote + 256;                             // 16 x 32-u32 (fallback)
    unsigned* fbar = vote + 1024;                            // 16 x 16 x 4-u32 (fast)

    convert_wh_frag<<<dim3(512),     dim3(256), 0, stream>>>(Wh, Wf);
    convert_wx_frag<<<dim3(64),      dim3(256), 0, stream>>>(Wx, Wxf);
    embed_gather_frag<<<dim3(10240), dim3(256), 0, stream>>>(inputs, emb, xe);
    hipMemsetAsync(hA, 0, (size_t)BATCH * UDIM * sizeof(_Float16), stream);
    hipMemsetAsync(vote, 0, 8192, stream);

    rnn_persist<<<dim3(256), dim3(512), 0, stream>>>(hA, hB, xe, Wf, Wxf, b,
                                                     vote, barg, bar, fbar);

    // T=80 even -> final h in hA
    out_proj<<<dim3(1024), dim3(256), 0, stream>>>(hA, Wo, bo, out);
}